// Round 2
// baseline (15062.061 us; speedup 1.0000x reference)
//
#include <hip/hip_runtime.h>

typedef float f4 __attribute__((ext_vector_type(4)));

#define NT 256
#define BB 128
#define BT 100
#define DZc 64
#define DAc 32
#define DUc 8
#define KMIX 8
#define DOBSc 16
#define HG 128
#define DINc 56   // DA + DOBS + DU

// flat element offsets into d_out (return order of the reference tuple)
#define O_ZFILT   0LL
#define O_PFILT   819200LL
#define O_ZPRED   53248000LL
#define O_AFILT   54067200LL
#define O_APRED   54476800LL
#define O_PPRED   54886400LL
#define O_ALPHA   107315200LL
#define O_ASEQ    107417600LL
#define O_BSEQ    159846400LL
#define O_CSEQ    166400000LL
#define O_ZMEAN   192614400LL
#define O_LTRIL   193433600LL
#define O_SPRED   245862400LL

__device__ __forceinline__ float dot4(f4 a, f4 b) {
    return a[0]*b[0] + a[1]*b[1] + a[2]*b[2] + a[3]*b[3];
}

struct SMem {
    float P[DZc][68];    // covariance carry (P_pred -> P_filt -> P_pred)
    float A[DZc][68];    // mixed A
    float Wk[DZc][68];   // temp: G = X^T CP ; then A@P_filt
    float Qm[DZc][68];   // Q cached
    float C[DAc][68];    // mixed C
    float CP[DAc][68];   // C@P
    float Xm[DAc][68];   // X = S^{-1} C P
    float S[DAc][33];    // innovation cov
    float Rm[DAc][33];   // R cached
    float Bm[DZc][8];    // mixed B
    float z[DZc], zp[DZc], zn[DZc];
    float h[HG];
    float gh[3*HG], gip[3*HG], gi[3*HG];
    float x[64];
    float ak[DAc], rvec[DAc];
    float u[8];
    float alpha[8];
    float mk;
};

template<bool EMIT>
__device__ __forceinline__ void softmax_mix(SMem& s, int tid, size_t bt,
    const float* __restrict__ A_mats, const float* __restrict__ B_mats,
    const float* __restrict__ C_mats, float* __restrict__ out)
{
    float lg[8];
    #pragma unroll
    for (int k = 0; k < 8; ++k) lg[k] = s.alpha[k];
    float mx = lg[0];
    #pragma unroll
    for (int k = 1; k < 8; ++k) mx = fmaxf(mx, lg[k]);
    float al[8]; float sum = 0.f;
    #pragma unroll
    for (int k = 0; k < 8; ++k) { al[k] = expf(lg[k] - mx); sum += al[k]; }
    float rs = 1.f / sum;
    #pragma unroll
    for (int k = 0; k < 8; ++k) al[k] *= rs;
    if (EMIT && tid < 8) out[O_ALPHA + bt*8 + tid] = al[tid];
    const f4* A4 = (const f4*)A_mats;
    const f4* B4 = (const f4*)B_mats;
    const f4* C4 = (const f4*)C_mats;
    #pragma unroll
    for (int e = 0; e < 4; ++e) {
        int i4 = tid + e*256;
        f4 acc = {0.f,0.f,0.f,0.f};
        #pragma unroll
        for (int k = 0; k < 8; ++k) acc += al[k] * A4[k*1024 + i4];
        *(f4*)&s.A[i4>>4][(i4&15)*4] = acc;
        if (EMIT) *(f4*)&out[O_ASEQ + bt*4096 + (size_t)i4*4] = acc;
    }
    if (tid < 128) {
        int i4 = tid;
        f4 acc = {0.f,0.f,0.f,0.f};
        #pragma unroll
        for (int k = 0; k < 8; ++k) acc += al[k] * B4[k*128 + i4];
        *(f4*)&s.Bm[i4>>1][(i4&1)*4] = acc;
        if (EMIT) *(f4*)&out[O_BSEQ + bt*512 + (size_t)i4*4] = acc;
    }
    #pragma unroll
    for (int e = 0; e < 2; ++e) {
        int i4 = tid + e*256;
        f4 acc = {0.f,0.f,0.f,0.f};
        #pragma unroll
        for (int k = 0; k < 8; ++k) acc += al[k] * C4[k*512 + i4];
        *(f4*)&s.C[i4>>4][(i4&15)*4] = acc;
    }
}

__global__ void __launch_bounds__(NT, 1)
kalman_seq(const float* __restrict__ a_seq, const float* __restrict__ h_obs,
           const float* __restrict__ u_seq, const float* __restrict__ mask,
           const float* __restrict__ A_mats, const float* __restrict__ B_mats,
           const float* __restrict__ C_mats, const float* __restrict__ a_0,
           const float* __restrict__ P_0, const float* __restrict__ Q,
           const float* __restrict__ R, const float* __restrict__ W_ih,
           const float* __restrict__ W_hh, const float* __restrict__ b_ih,
           const float* __restrict__ b_hh, const float* __restrict__ W_out,
           const float* __restrict__ b_out, float* __restrict__ out)
{
    __shared__ SMem s;
    const int b = blockIdx.x;
    const int tid = threadIdx.x;
    const int r4 = (tid >> 4) << 2;   // 4-row base (64-row tiles)
    const int c4 = (tid & 15) << 2;   // 4-col base (64-col tiles)
    const int r2 = (tid >> 4) << 1;   // 2-row base (32-row tiles)
    const int c2 = (tid & 15) << 1;   // 2-col base (32-col tiles)

    // ---------------- init ----------------
    for (int idx = tid; idx < DZc*DZc; idx += NT) {
        s.P[idx >> 6][idx & 63]  = P_0[idx];
        s.Qm[idx >> 6][idx & 63] = Q[idx];
    }
    for (int idx = tid; idx < DAc*DAc; idx += NT) s.Rm[idx >> 5][idx & 31] = R[idx];
    if (tid < HG) s.h[tid] = 0.f;
    if (tid < DZc) s.z[tid] = 0.f;
    if (tid < DAc)                 s.x[tid] = a_0[tid];
    else if (tid < DAc + DOBSc)    s.x[tid] = h_obs[b*DOBSc + (tid - DAc)];
    else if (tid < DINc)           s.x[tid] = u_seq[(size_t)b*BT*DUc + (tid - DAc - DOBSc)];
    __syncthreads();

    // init alpha_net (h = 0 -> gh = b_hh exactly)
    for (int g = tid; g < 3*HG; g += NT) {
        float acc = b_ih[g];
        const float* wr = W_ih + (size_t)g * DINc;
        #pragma unroll
        for (int d = 0; d < DINc; ++d) acc += wr[d] * s.x[d];
        s.gi[g] = acc;
        s.gh[g] = b_hh[g];
    }
    __syncthreads();
    if (tid < HG) {
        float r  = 1.f / (1.f + expf(-(s.gi[tid] + s.gh[tid])));
        float zg = 1.f / (1.f + expf(-(s.gi[HG+tid] + s.gh[HG+tid])));
        float n  = tanhf(s.gi[2*HG+tid] + r * s.gh[2*HG+tid]);
        s.h[tid] = (1.f - zg) * n + zg * s.h[tid];
    }
    __syncthreads();
    if (tid < KMIX) {
        float acc = b_out[tid];
        const float* wr = W_out + tid * HG;
        #pragma unroll 8
        for (int d = 0; d < HG; ++d) acc += wr[d] * s.h[d];
        s.alpha[tid] = acc;   // logits
    }
    __syncthreads();
    softmax_mix<false>(s, tid, 0, A_mats, B_mats, C_mats, out);
    __syncthreads();

    for (int t = 0; t < BT; ++t) {
        const size_t bt = (size_t)b * BT + t;

        // ---- S0: zp = A z + B u ; load step inputs ----
        if (tid < DZc) {
            float acc = 0.f;
            #pragma unroll
            for (int k4 = 0; k4 < 16; ++k4) {
                f4 a = *(const f4*)&s.A[tid][k4*4];
                f4 zv = *(const f4*)&s.z[k4*4];
                acc += dot4(a, zv);
            }
            const float* up = u_seq + bt*DUc;
            #pragma unroll
            for (int q = 0; q < DUc; ++q) acc += s.Bm[tid][q] * up[q];
            s.zp[tid] = acc;
        } else if (tid < 96) {
            s.ak[tid-64] = a_seq[bt*DAc + (tid-64)];
        } else if (tid < 104) {
            float uv = u_seq[bt*DUc + (tid-96)];
            s.u[tid-96] = uv; s.x[48 + (tid-96)] = uv;
        } else if (tid == 104) {
            s.mk = mask[bt];
        }
        __syncthreads();
        const float mkv = s.mk;

        // ---- S1: CP = C @ P ; rvec = ak - C zp ----
        {
            float acc[2][4] = {{0.f,0.f,0.f,0.f},{0.f,0.f,0.f,0.f}};
            #pragma unroll 8
            for (int k = 0; k < DZc; ++k) {
                float a0 = s.C[r2][k], a1 = s.C[r2+1][k];
                f4 bv = *(const f4*)&s.P[k][c4];
                #pragma unroll
                for (int j = 0; j < 4; ++j) { acc[0][j] += a0*bv[j]; acc[1][j] += a1*bv[j]; }
            }
            f4 v0 = {acc[0][0],acc[0][1],acc[0][2],acc[0][3]};
            f4 v1 = {acc[1][0],acc[1][1],acc[1][2],acc[1][3]};
            *(f4*)&s.CP[r2][c4] = v0;
            *(f4*)&s.CP[r2+1][c4] = v1;
        }
        if (tid < DAc) {
            float acc = 0.f;
            #pragma unroll
            for (int k4 = 0; k4 < 16; ++k4)
                acc += dot4(*(const f4*)&s.C[tid][k4*4], *(const f4*)&s.zp[k4*4]);
            s.rvec[tid] = s.ak[tid] - acc;
        }
        __syncthreads();

        // ---- S2: S = CP C^T + R ; emit S_pred ----
        {
            float acc[2][2] = {{0.f,0.f},{0.f,0.f}};
            #pragma unroll
            for (int k4 = 0; k4 < 16; ++k4) {
                f4 a0 = *(const f4*)&s.CP[r2][k4*4];
                f4 a1 = *(const f4*)&s.CP[r2+1][k4*4];
                f4 b0 = *(const f4*)&s.C[c2][k4*4];
                f4 b1 = *(const f4*)&s.C[c2+1][k4*4];
                acc[0][0] += dot4(a0,b0); acc[0][1] += dot4(a0,b1);
                acc[1][0] += dot4(a1,b0); acc[1][1] += dot4(a1,b1);
            }
            #pragma unroll
            for (int i = 0; i < 2; ++i)
                #pragma unroll
                for (int j = 0; j < 2; ++j) {
                    float v = acc[i][j] + s.Rm[r2+i][c2+j];
                    s.S[r2+i][c2+j] = v;
                    out[O_SPRED + bt*DAc*DAc + (size_t)(r2+i)*DAc + (c2+j)] = v;
                }
        }
        __syncthreads();

        // ---- S3: wave 0: chol32 + solves (registers + shfl, no barriers)
        //          waves 1-3: gh = W_hh h + b_hh ; gip = partial gi (d>=32) ----
        if (tid < 64) {
            const int lane = tid;
            const int rl = lane & 31;
            float row[32], linv[32];
            #pragma unroll
            for (int k = 0; k < 32; ++k) row[k] = s.S[rl][k];
            #pragma unroll
            for (int k = 0; k < 32; ++k) {
                float acc = row[k];
                #pragma unroll
                for (int m = 0; m < k; ++m) acc -= row[m] * __shfl(row[m], k);
                float d = sqrtf(__shfl(acc, k));
                float inv = 1.0f / d;
                linv[k] = inv;
                row[k] = (rl == k) ? d : acc * inv;
            }
            float cp[32];
            #pragma unroll
            for (int r = 0; r < 32; ++r) cp[r] = s.CP[r][lane];
            #pragma unroll
            for (int r = 0; r < 32; ++r) {          // L y = cp
                float acc = cp[r];
                #pragma unroll
                for (int k = 0; k < r; ++k) acc -= __shfl(row[k], r) * cp[k];
                cp[r] = acc * linv[r];
            }
            #pragma unroll
            for (int r = 31; r >= 0; --r) {         // L^T x = y
                float acc = cp[r];
                #pragma unroll
                for (int k = r+1; k < 32; ++k) acc -= __shfl(row[r], k) * cp[k];
                cp[r] = acc * linv[r];
            }
            #pragma unroll
            for (int r = 0; r < 32; ++r) s.Xm[r][lane] = cp[r];
            float accz = 0.f;
            #pragma unroll
            for (int r = 0; r < 32; ++r) accz += cp[r] * s.rvec[r];
            s.zn[lane] = s.zp[lane] + mkv * accz;
        } else {
            const int grp = (tid - 64) >> 5;        // 0..5
            const int lane = tid & 31;
            f4 hv = *(const f4*)&s.h[lane*4];
            float xl = (lane < 24) ? s.x[32 + lane] : 0.f;
            for (int g = grp; g < 3*HG; g += 6) {
                const f4 w = *(const f4*)(W_hh + (size_t)g*HG + lane*4);
                float acc = dot4(hv, w);
                float acc2 = (lane < 24) ? (W_ih[(size_t)g*DINc + 32 + lane] * xl) : 0.f;
                #pragma unroll
                for (int m = 16; m >= 1; m >>= 1) {
                    acc += __shfl_xor(acc, m);
                    acc2 += __shfl_xor(acc2, m);
                }
                if (lane == 0) { s.gh[g] = acc + b_hh[g]; s.gip[g] = acc2 + b_ih[g]; }
            }
        }
        __syncthreads();

        // ---- S4: G = X^T CP  (into Wk) ----
        {
            float acc[4][4] = {{0.f,0.f,0.f,0.f},{0.f,0.f,0.f,0.f},{0.f,0.f,0.f,0.f},{0.f,0.f,0.f,0.f}};
            #pragma unroll 4
            for (int l = 0; l < DAc; ++l) {
                f4 bv = *(const f4*)&s.CP[l][c4];
                float a0 = s.Xm[l][r4], a1 = s.Xm[l][r4+1], a2 = s.Xm[l][r4+2], a3 = s.Xm[l][r4+3];
                #pragma unroll
                for (int j = 0; j < 4; ++j) {
                    acc[0][j] += a0*bv[j]; acc[1][j] += a1*bv[j];
                    acc[2][j] += a2*bv[j]; acc[3][j] += a3*bv[j];
                }
            }
            #pragma unroll
            for (int i = 0; i < 4; ++i) {
                f4 v = {acc[i][0],acc[i][1],acc[i][2],acc[i][3]};
                *(f4*)&s.Wk[r4+i][c4] = v;
            }
        }
        __syncthreads();

        // ---- S5: P_filt = P + (mk^2-2mk)*sym(G) ; emits ; a_filt ; x update ----
        {
            const float coef = mkv*mkv - 2.f*mkv;
            f4 gcol[4];
            #pragma unroll
            for (int j = 0; j < 4; ++j) gcol[j] = *(const f4*)&s.Wk[c4+j][r4];
            #pragma unroll
            for (int i = 0; i < 4; ++i) {
                f4 grow = *(const f4*)&s.Wk[r4+i][c4];
                f4 p = *(const f4*)&s.P[r4+i][c4];
                f4 v;
                #pragma unroll
                for (int j = 0; j < 4; ++j)
                    v[j] = p[j] + coef * 0.5f * (grow[j] + gcol[j][i]);
                *(f4*)&s.P[r4+i][c4] = v;
                *(f4*)&out[O_PFILT + bt*4096 + (size_t)(r4+i)*64 + c4] = v;
            }
        }
        if (tid < DZc) {
            float v = s.zn[tid];
            out[O_ZFILT + bt*DZc + tid] = v;
            out[O_ZMEAN + bt*DZc + tid] = v;
            s.z[tid] = v;
        }
        if (tid < DAc) {
            float acc = 0.f;
            #pragma unroll
            for (int k4 = 0; k4 < 16; ++k4)
                acc += dot4(*(const f4*)&s.C[tid][k4*4], *(const f4*)&s.zn[k4*4]);
            out[O_AFILT + bt*DAc + tid] = acc;
            s.x[tid] = mkv * s.ak[tid] + (1.f - mkv) * acc;   // a_k_hat
        }
        #pragma unroll
        for (int e = 0; e < 2; ++e) {
            int i4 = tid + e*256;
            *(f4*)&out[O_CSEQ + bt*2048 + (size_t)i4*4] = *(const f4*)&s.C[i4>>4][(i4&15)*4];
        }
        __syncthreads();

        // ---- S6: gi = W_ih[:, :32] x[:32] + gip ----
        {
            const int grp8 = tid >> 5;
            const int lane = tid & 31;
            float xl = s.x[lane];
            for (int g = grp8; g < 3*HG; g += 8) {
                float acc = W_ih[(size_t)g*DINc + lane] * xl;
                #pragma unroll
                for (int m = 16; m >= 1; m >>= 1) acc += __shfl_xor(acc, m);
                if (lane == 0) s.gi[g] = acc + s.gip[g];
            }
        }
        __syncthreads();

        // ---- S7: GRU gates, h update ----
        if (tid < HG) {
            float gi0 = s.gi[tid], gi1 = s.gi[HG+tid], gi2 = s.gi[2*HG+tid];
            float gh0 = s.gh[tid], gh1 = s.gh[HG+tid], gh2 = s.gh[2*HG+tid];
            float hold = s.h[tid];
            float r  = 1.f / (1.f + expf(-(gi0 + gh0)));
            float zg = 1.f / (1.f + expf(-(gi1 + gh1)));
            float n  = tanhf(gi2 + r * gh2);
            s.h[tid] = (1.f - zg) * n + zg * hold;
        }
        __syncthreads();

        // ---- S8: logits ----
        {
            const int g = tid >> 5;
            const int lane = tid & 31;
            f4 hv = *(const f4*)&s.h[lane*4];
            const f4 w = *(const f4*)(W_out + (size_t)g*HG + lane*4);
            float acc = dot4(hv, w);
            #pragma unroll
            for (int m = 16; m >= 1; m >>= 1) acc += __shfl_xor(acc, m);
            if (lane == 0) s.alpha[g] = acc + b_out[g];
        }
        __syncthreads();

        // ---- S9: softmax (replicated) + mix + emit alpha/A_seq/B_seq ----
        softmax_mix<true>(s, tid, bt, A_mats, B_mats, C_mats, out);
        __syncthreads();

        // ---- S10: Wk = A @ P_filt ; z_pred ----
        if (tid < DZc) {
            float acc = 0.f;
            #pragma unroll
            for (int k4 = 0; k4 < 16; ++k4)
                acc += dot4(*(const f4*)&s.A[tid][k4*4], *(const f4*)&s.z[k4*4]);
            f4 b0 = *(const f4*)&s.Bm[tid][0];
            f4 b1 = *(const f4*)&s.Bm[tid][4];
            f4 u0 = *(const f4*)&s.u[0];
            f4 u1 = *(const f4*)&s.u[4];
            acc += dot4(b0,u0) + dot4(b1,u1);
            s.zp[tid] = acc;
            out[O_ZPRED + bt*DZc + tid] = acc;
        }
        {
            float acc[4][4] = {{0.f,0.f,0.f,0.f},{0.f,0.f,0.f,0.f},{0.f,0.f,0.f,0.f},{0.f,0.f,0.f,0.f}};
            #pragma unroll
            for (int k4 = 0; k4 < 16; ++k4) {
                f4 ar[4];
                #pragma unroll
                for (int i = 0; i < 4; ++i) ar[i] = *(const f4*)&s.A[r4+i][k4*4];
                #pragma unroll
                for (int kk = 0; kk < 4; ++kk) {
                    f4 bv = *(const f4*)&s.P[k4*4+kk][c4];
                    #pragma unroll
                    for (int i = 0; i < 4; ++i) {
                        float av = ar[i][kk];
                        #pragma unroll
                        for (int j = 0; j < 4; ++j) acc[i][j] += av * bv[j];
                    }
                }
            }
            #pragma unroll
            for (int i = 0; i < 4; ++i) {
                f4 v = {acc[i][0],acc[i][1],acc[i][2],acc[i][3]};
                *(f4*)&s.Wk[r4+i][c4] = v;
            }
        }
        __syncthreads();

        // ---- S11: P_raw = Wk @ A^T + Q -> P ; a_pred ----
        {
            float acc[4][4] = {{0.f,0.f,0.f,0.f},{0.f,0.f,0.f,0.f},{0.f,0.f,0.f,0.f},{0.f,0.f,0.f,0.f}};
            #pragma unroll
            for (int k4 = 0; k4 < 16; ++k4) {
                f4 w0 = *(const f4*)&s.Wk[r4+0][k4*4];
                f4 w1 = *(const f4*)&s.Wk[r4+1][k4*4];
                f4 w2 = *(const f4*)&s.Wk[r4+2][k4*4];
                f4 w3 = *(const f4*)&s.Wk[r4+3][k4*4];
                #pragma unroll
                for (int j = 0; j < 4; ++j) {
                    f4 a = *(const f4*)&s.A[c4+j][k4*4];
                    acc[0][j] += dot4(w0,a); acc[1][j] += dot4(w1,a);
                    acc[2][j] += dot4(w2,a); acc[3][j] += dot4(w3,a);
                }
            }
            #pragma unroll
            for (int i = 0; i < 4; ++i) {
                f4 q = *(const f4*)&s.Qm[r4+i][c4];
                f4 v = {acc[i][0]+q[0],acc[i][1]+q[1],acc[i][2]+q[2],acc[i][3]+q[3]};
                *(f4*)&s.P[r4+i][c4] = v;
            }
        }
        if (tid < DAc) {
            float acc = 0.f;
            #pragma unroll
            for (int k4 = 0; k4 < 16; ++k4)
                acc += dot4(*(const f4*)&s.C[tid][k4*4], *(const f4*)&s.zp[k4*4]);
            out[O_APRED + bt*DAc + tid] = acc;
        }
        __syncthreads();

        // ---- S12: symmetrize P_pred in place + emit (no trailing barrier) ----
        for (int idx = tid; idx < DZc*DZc; idx += NT) {
            int i = idx >> 6, j = idx & 63;
            if (i <= j) {
                float v = 0.5f * (s.P[i][j] + s.P[j][i]);
                s.P[i][j] = v; s.P[j][i] = v;
                out[O_PPRED + bt*4096 + (size_t)i*64 + j] = v;
                out[O_PPRED + bt*4096 + (size_t)j*64 + i] = v;
            }
        }
        // next S0 writes zp/ak/u/mk only; S1 reads P after next barrier -> safe
    }
}

// ---- kernel 2: batched 64x64 Cholesky (register + shfl, 1 wave/block) ----
__global__ void __launch_bounds__(64, 4)
chol_batch(float* __restrict__ out)
{
    __shared__ float M[DZc][68];
    const size_t bt = blockIdx.x;
    const int lane = threadIdx.x;
    const float* src = out + O_PFILT + bt*4096;
    #pragma unroll
    for (int e = 0; e < 16; ++e) {
        int i4 = lane + e*64;
        f4 v = *(const f4*)(src + (size_t)i4*4);
        *(f4*)&M[i4>>4][(i4&15)*4] = v;
    }
    __syncthreads();
    float row[64];
    #pragma unroll
    for (int k = 0; k < 64; ++k) row[k] = M[lane][k];
    row[lane] += 2.0e-4f;   // + 2*JITTER
    #pragma unroll
    for (int k = 0; k < 64; ++k) {
        float acc = row[k];
        #pragma unroll
        for (int m = 0; m < k; ++m) acc -= row[m] * __shfl(row[m], k);
        float d = sqrtf(__shfl(acc, k));
        float inv = 1.0f / d;
        row[k] = (lane == k) ? d : acc * inv;
    }
    #pragma unroll
    for (int k = 0; k < 64; ++k) M[lane][k] = (k <= lane) ? row[k] : 0.f;
    __syncthreads();
    float* dst = out + O_LTRIL + bt*4096;
    #pragma unroll
    for (int e = 0; e < 16; ++e) {
        int i4 = lane + e*64;
        *(f4*)(dst + (size_t)i4*4) = *(const f4*)&M[i4>>4][(i4&15)*4];
    }
}

extern "C" void kernel_launch(void* const* d_in, const int* in_sizes, int n_in,
                              void* d_out, int out_size, void* d_ws, size_t ws_size,
                              hipStream_t stream) {
    const float* a_seq  = (const float*)d_in[0];
    const float* h_obs  = (const float*)d_in[1];
    const float* u_seq  = (const float*)d_in[2];
    const float* mask   = (const float*)d_in[3];
    const float* A_mats = (const float*)d_in[4];
    const float* B_mats = (const float*)d_in[5];
    const float* C_mats = (const float*)d_in[6];
    const float* a_0    = (const float*)d_in[7];
    const float* P_0    = (const float*)d_in[8];
    const float* Q      = (const float*)d_in[9];
    const float* R      = (const float*)d_in[10];
    const float* W_ih   = (const float*)d_in[11];
    const float* W_hh   = (const float*)d_in[12];
    const float* b_ih   = (const float*)d_in[13];
    const float* b_hh   = (const float*)d_in[14];
    const float* W_out  = (const float*)d_in[15];
    const float* b_out  = (const float*)d_in[16];
    float* out = (float*)d_out;

    kalman_seq<<<dim3(BB), dim3(NT), 0, stream>>>(a_seq, h_obs, u_seq, mask,
        A_mats, B_mats, C_mats, a_0, P_0, Q, R, W_ih, W_hh, b_ih, b_hh, W_out, b_out, out);
    chol_batch<<<dim3(BB*BT), dim3(64), 0, stream>>>(out);
}